// Round 13
// baseline (72.967 us; speedup 1.0000x reference)
//
#include <hip/hip_runtime.h>

#define NCLS 19
#define CM_BINS (NCLS * NCLS)   // 361
#define EPS 1e-5f
#define HW 262144               // 512*512
#define HW8 32768               // HW/8
#define BLOCK 256
#define GRID 512                // scan optimum (4096=100.6, 2048=76.7, 1024=66.9, 512=63.3, 256=64.5)

typedef float f32x4 __attribute__((ext_vector_type(4)));
typedef int   i32x4 __attribute__((ext_vector_type(4)));

__global__ void __launch_bounds__(BLOCK)
dice_cm_kernel(const float* __restrict__ y_pred,
               const int* __restrict__ y,
               unsigned int* __restrict__ cm,
               int n_oct) {
    __shared__ unsigned int s_cm[CM_BINS];
    const int tid = threadIdx.x;
    for (int i = tid; i < CM_BINS; i += BLOCK) s_cm[i] = 0u;
    __syncthreads();

    // 8 px/thread: two f32x4 per plane, all 40 loads of an iteration issue
    // as one burst -> half the load-drain points vs 4 px/thread (R12 theory:
    // compare/atomic tail leaves HBM idle at 2 waves/SIMD). Fixed ascending
    // plane order, strict > = jnp.argmax first-occurrence.
    for (int pv = blockIdx.x * BLOCK + tid; pv < n_oct; pv += GRID * BLOCK) {
        const int b   = pv >> 15;        // pv / HW8
        const int hw8 = pv & 32767;      // pv % HW8
        const float* p = y_pred + (size_t)b * ((size_t)NCLS * HW) + (size_t)hw8 * 8;

        f32x4 best0 = __builtin_nontemporal_load(reinterpret_cast<const f32x4*>(p));
        f32x4 best1 = __builtin_nontemporal_load(reinterpret_cast<const f32x4*>(p + 4));
        int bc0x = 0, bc0y = 0, bc0z = 0, bc0w = 0;
        int bc1x = 0, bc1y = 0, bc1z = 0, bc1w = 0;
        #pragma unroll
        for (int c = 1; c < NCLS; ++c) {
            const f32x4 v0 = __builtin_nontemporal_load(
                reinterpret_cast<const f32x4*>(p + (size_t)c * HW));
            const f32x4 v1 = __builtin_nontemporal_load(
                reinterpret_cast<const f32x4*>(p + (size_t)c * HW + 4));
            if (v0.x > best0.x) { best0.x = v0.x; bc0x = c; }
            if (v0.y > best0.y) { best0.y = v0.y; bc0y = c; }
            if (v0.z > best0.z) { best0.z = v0.z; bc0z = c; }
            if (v0.w > best0.w) { best0.w = v0.w; bc0w = c; }
            if (v1.x > best1.x) { best1.x = v1.x; bc1x = c; }
            if (v1.y > best1.y) { best1.y = v1.y; bc1y = c; }
            if (v1.z > best1.z) { best1.z = v1.z; bc1z = c; }
            if (v1.w > best1.w) { best1.w = v1.w; bc1w = c; }
        }

        const i32x4 lab0 = __builtin_nontemporal_load(
            reinterpret_cast<const i32x4*>(y) + pv * 2);
        const i32x4 lab1 = __builtin_nontemporal_load(
            reinterpret_cast<const i32x4*>(y) + pv * 2 + 1);

        atomicAdd(&s_cm[lab0.x * NCLS + bc0x], 1u);
        atomicAdd(&s_cm[lab0.y * NCLS + bc0y], 1u);
        atomicAdd(&s_cm[lab0.z * NCLS + bc0z], 1u);
        atomicAdd(&s_cm[lab0.w * NCLS + bc0w], 1u);
        atomicAdd(&s_cm[lab1.x * NCLS + bc1x], 1u);
        atomicAdd(&s_cm[lab1.y * NCLS + bc1y], 1u);
        atomicAdd(&s_cm[lab1.z * NCLS + bc1z], 1u);
        atomicAdd(&s_cm[lab1.w * NCLS + bc1w], 1u);
    }

    __syncthreads();
    for (int i = tid; i < CM_BINS; i += BLOCK) {
        const unsigned int v = s_cm[i];
        if (v) atomicAdd(&cm[i], v);
    }
}

__global__ void dice_finalize(const unsigned int* __restrict__ cm,
                              float* __restrict__ out) {
    const int lane = threadIdx.x;
    float d = 0.0f;
    if (lane < NCLS) {
        float cy = 0.0f, cp = 0.0f;
        #pragma unroll
        for (int j = 0; j < NCLS; ++j) {
            cy += (float)cm[lane * NCLS + j];   // row sum: |y==lane|
            cp += (float)cm[j * NCLS + lane];   // col sum: |pred==lane|
        }
        const float inter = (float)cm[lane * NCLS + lane];
        const float uni   = cy + cp - inter;
        d = (2.0f * inter + EPS) / (uni + EPS);
    }
    #pragma unroll
    for (int off = 32; off > 0; off >>= 1) d += __shfl_down(d, off);
    if (lane == 0) out[0] = 1.0f - d * (1.0f / (float)NCLS);
}

extern "C" void kernel_launch(void* const* d_in, const int* in_sizes, int n_in,
                              void* d_out, int out_size, void* d_ws, size_t ws_size,
                              hipStream_t stream) {
    const float* y_pred = (const float*)d_in[0];
    const int*   y      = (const int*)d_in[1];
    float*       out    = (float*)d_out;
    unsigned int* cm    = (unsigned int*)d_ws;

    // zero the 361-bin confusion matrix (harness poisons d_ws with 0xAA)
    hipMemsetAsync(cm, 0, CM_BINS * sizeof(unsigned int), stream);

    const int n_pix = in_sizes[1];     // 16*512*512
    const int n_oct = n_pix / 8;       // 524,288 -> exactly 4 iters/thread

    dice_cm_kernel<<<GRID, BLOCK, 0, stream>>>(y_pred, y, cm, n_oct);
    dice_finalize<<<1, 64, 0, stream>>>(cm, out);
}

// Round 14
// 63.033 us; speedup vs baseline: 1.1576x; 1.1576x over previous
//
#include <hip/hip_runtime.h>

#define NCLS 19
#define CM_BINS (NCLS * NCLS)   // 361
#define EPS 1e-5f
#define HW 262144               // 512*512
#define BLOCK 256
#define GRID 512                // scan optimum: {4096:100.6, 2048:76.7, 1024:66.9, 512:63.3, 256:64.5}

typedef float f32x4 __attribute__((ext_vector_type(4)));
typedef int   i32x4 __attribute__((ext_vector_type(4)));

__global__ void __launch_bounds__(BLOCK)
dice_cm_kernel(const float* __restrict__ y_pred,
               const int* __restrict__ y,
               unsigned int* __restrict__ cm,
               int n_vec) {
    __shared__ unsigned int s_cm[CM_BINS];
    const int tid = threadIdx.x;
    for (int i = tid; i < CM_BINS; i += BLOCK) s_cm[i] = 0u;
    __syncthreads();

    // Locked structure (scan results):
    //  - 4 px/thread, one 20-load f32x4 burst per iteration
    //    (R3/R13: both narrower and wider bursts regress)
    //  - fixed ascending plane order, strict > = jnp.argmax first-occurrence
    //    (R7: runtime-rotated order serialized address calc, -24%)
    //  - GRID=512: per-block cost (LDS zero + 361-bin atomic flush)
    //    amortized; 256 loses prologue/tail coverage (R12)
    //  - separate tiny finalize kernel (R4: fused last-block-done w/
    //    threadfence per block = 2x regression)
    for (int pv = blockIdx.x * BLOCK + tid; pv < n_vec; pv += GRID * BLOCK) {
        const int b   = pv >> 16;        // pv / (HW/4)
        const int hw4 = pv & 65535;      // pv % (HW/4)
        const float* p = y_pred + (size_t)b * ((size_t)NCLS * HW) + (size_t)hw4 * 4;

        f32x4 best = __builtin_nontemporal_load(reinterpret_cast<const f32x4*>(p));
        int bcx = 0, bcy = 0, bcz = 0, bcw = 0;
        #pragma unroll
        for (int c = 1; c < NCLS; ++c) {
            const f32x4 v = __builtin_nontemporal_load(
                reinterpret_cast<const f32x4*>(p + (size_t)c * HW));
            if (v.x > best.x) { best.x = v.x; bcx = c; }
            if (v.y > best.y) { best.y = v.y; bcy = c; }
            if (v.z > best.z) { best.z = v.z; bcz = c; }
            if (v.w > best.w) { best.w = v.w; bcw = c; }
        }

        const i32x4 lab = __builtin_nontemporal_load(
            reinterpret_cast<const i32x4*>(y) + pv);

        atomicAdd(&s_cm[lab.x * NCLS + bcx], 1u);
        atomicAdd(&s_cm[lab.y * NCLS + bcy], 1u);
        atomicAdd(&s_cm[lab.z * NCLS + bcz], 1u);
        atomicAdd(&s_cm[lab.w * NCLS + bcw], 1u);
    }

    __syncthreads();
    for (int i = tid; i < CM_BINS; i += BLOCK) {
        const unsigned int v = s_cm[i];
        if (v) atomicAdd(&cm[i], v);
    }
}

__global__ void dice_finalize(const unsigned int* __restrict__ cm,
                              float* __restrict__ out) {
    const int lane = threadIdx.x;
    float d = 0.0f;
    if (lane < NCLS) {
        float cy = 0.0f, cp = 0.0f;
        #pragma unroll
        for (int j = 0; j < NCLS; ++j) {
            cy += (float)cm[lane * NCLS + j];   // row sum: |y==lane|
            cp += (float)cm[j * NCLS + lane];   // col sum: |pred==lane|
        }
        const float inter = (float)cm[lane * NCLS + lane];
        const float uni   = cy + cp - inter;
        d = (2.0f * inter + EPS) / (uni + EPS);
    }
    #pragma unroll
    for (int off = 32; off > 0; off >>= 1) d += __shfl_down(d, off);
    if (lane == 0) out[0] = 1.0f - d * (1.0f / (float)NCLS);
}

extern "C" void kernel_launch(void* const* d_in, const int* in_sizes, int n_in,
                              void* d_out, int out_size, void* d_ws, size_t ws_size,
                              hipStream_t stream) {
    const float* y_pred = (const float*)d_in[0];
    const int*   y      = (const int*)d_in[1];
    float*       out    = (float*)d_out;
    unsigned int* cm    = (unsigned int*)d_ws;

    // zero the 361-bin confusion matrix (harness poisons d_ws with 0xAA)
    hipMemsetAsync(cm, 0, CM_BINS * sizeof(unsigned int), stream);

    const int n_pix = in_sizes[1];     // 16*512*512
    const int n_vec = n_pix / 4;       // 1,048,576 -> exactly 8 iters/thread

    dice_cm_kernel<<<GRID, BLOCK, 0, stream>>>(y_pred, y, cm, n_vec);
    dice_finalize<<<1, 64, 0, stream>>>(cm, out);
}